// Round 1
// baseline (1588.611 us; speedup 1.0000x reference)
//
#include <hip/hip_runtime.h>
#include <math.h>

#define BN 2
#define NN 1024
#define DDIM 256
#define HH 8
#define HDIM 32
#define FFD 1024
#define EPSV 1e-5f
#define SCALEV 0.17677669529663687f

__device__ __forceinline__ float gelu_f(float x){
  return 0.5f*x*(1.0f+erff(x*0.70710678118654752f));
}

// ---------------- LayerNorm: one block per row (256 threads, D=256) ----------
__global__ __launch_bounds__(256) void ln_kernel(const float* __restrict__ x,
    const float* __restrict__ g, const float* __restrict__ b, float* __restrict__ out){
  int row = blockIdx.x, tid = threadIdx.x;
  float val = x[(size_t)row*DDIM + tid];
  float s = val;
  #pragma unroll
  for (int o=32;o;o>>=1) s += __shfl_xor(s,o);
  __shared__ float sb[4], sb2[4];
  if ((tid&63)==0) sb[tid>>6]=s;
  __syncthreads();
  float mean = (sb[0]+sb[1]+sb[2]+sb[3]) * (1.0f/DDIM);
  float d = val-mean;
  float vs = d*d;
  #pragma unroll
  for (int o=32;o;o>>=1) vs += __shfl_xor(vs,o);
  if ((tid&63)==0) sb2[tid>>6]=vs;
  __syncthreads();
  float var = (sb2[0]+sb2[1]+sb2[2]+sb2[3]) * (1.0f/DDIM);
  out[(size_t)row*DDIM + tid] = d*rsqrtf(var+EPSV)*g[tid]+b[tid];
}

// ---------------- RoPE tables: sin/cos[i][d], i<1024, d<16 ------------------
__global__ __launch_bounds__(256) void rope_table(float* __restrict__ sint, float* __restrict__ cost){
  int idx = blockIdx.x*256+threadIdx.x;   // 16384
  int i = idx >> 4, d = idx & 15;
  float freq = (float)i * powf(10000.0f, -(float)d/16.0f);
  sint[idx]=sinf(freq); cost[idx]=cosf(freq);
}

// ------------- split qkv + rope; writes q,k,v in (B,H,N,HD) -----------------
__global__ __launch_bounds__(256) void rope_apply(const float* __restrict__ qkv,
    const float* __restrict__ sint, const float* __restrict__ cost,
    float* __restrict__ q, float* __restrict__ k, float* __restrict__ v){
  int row = blockIdx.x;                 // b*1024 + i
  int b = row>>10, i = row&1023;
  int tid = threadIdx.x; int h = tid>>5, d = tid&31;
  const float* base = qkv + (size_t)row*768;
  size_t oidx = (((size_t)(b*HH+h)*NN) + i)*HDIM + d;
  v[oidx] = base[512 + h*32 + d];
  int dd = (d<16) ? d : d-16;
  float s = sint[i*16+dd], c = cost[i*16+dd];
  float q1 = base[h*32+dd], q2 = base[h*32+dd+16];
  q[oidx] = (d<16) ? (q1*c - q2*s) : (q2*c + q1*s);
  float k1 = base[256+h*32+dd], k2 = base[256+h*32+dd+16];
  k[oidx] = (d<16) ? (k1*c - k2*s) : (k2*c + k1*s);
}

// ------------- rel bias MLP: thread per (b,i,j); writes (B,N,N,H) -----------
__global__ __launch_bounds__(256) void rel_kernel(const float* __restrict__ coords,
    const float* __restrict__ vel, const float* __restrict__ W1, const float* __restrict__ b1,
    const float* __restrict__ W2, const float* __restrict__ b2, float* __restrict__ rel){
  __shared__ float sW1[320], sW2[512], sb1[64], sb2[8];
  int tid = threadIdx.x;
  sW2[tid]=W2[tid]; sW2[tid+256]=W2[tid+256];
  if (tid<320) { /* covered below */ }
  if (tid<256) sW1[tid]=W1[tid];
  if (tid<64)  sW1[256+tid]=W1[256+tid];
  if (tid<64)  sb1[tid]=b1[tid];
  if (tid<8)   sb2[tid]=b2[tid];
  __syncthreads();
  size_t idx = (size_t)blockIdx.x*256 + tid;   // < 2*1024*1024
  int j = idx & 1023; int i = (int)((idx>>10)&1023); int b = (int)(idx>>20);
  const float* ci = coords + ((size_t)(b<<10)+i)*2;
  const float* cj = coords + ((size_t)(b<<10)+j)*2;
  const float* vi = vel    + ((size_t)(b<<10)+i)*2;
  const float* vj = vel    + ((size_t)(b<<10)+j)*2;
  float f0 = ci[0]-cj[0], f1 = ci[1]-cj[1];
  float f2 = sqrtf(f0*f0+f1*f1);
  float f3 = vi[0]-vj[0], f4 = vi[1]-vj[1];
  float o[8];
  #pragma unroll
  for (int hh=0;hh<8;++hh) o[hh]=sb2[hh];
  for (int r=0;r<64;++r){
    float t = sb1[r] + f0*sW1[r] + f1*sW1[64+r] + f2*sW1[128+r]
                     + f3*sW1[192+r] + f4*sW1[256+r];
    float gl = gelu_f(t);
    #pragma unroll
    for (int hh=0;hh<8;++hh) o[hh] = fmaf(gl, sW2[r*8+hh], o[hh]);
  }
  float* op = rel + idx*8;
  #pragma unroll
  for (int hh=0;hh<8;++hh) op[hh]=o[hh];
}

// ------------- attention: block per (b,h,i); softmax + PV fused -------------
__global__ __launch_bounds__(256) void attn_kernel(const float* __restrict__ q,
    const float* __restrict__ kk, const float* __restrict__ vv,
    const float* __restrict__ rel, float* __restrict__ out){
  int bh = blockIdx.x >> 10;          // b*8 + h
  int i  = blockIdx.x & 1023;
  int b = bh >> 3, h = bh & 7;
  int tid = threadIdx.x;
  __shared__ float qs[32];
  __shared__ float probs[1024];
  __shared__ float red[256];
  __shared__ float rb1[4], rb2[4];
  const float* kbase = kk + ((size_t)bh<<15);   // *1024*32
  const float* vbase = vv + ((size_t)bh<<15);
  if (tid < 32) qs[tid] = q[(((size_t)bh<<10) + i)*32 + tid];
  __syncthreads();
  const float* relbase = rel + ((((size_t)(b<<10)+i))<<13) + h;  // ((b*N+i)*N + j)*8 + h
  float sv[4]; float lmax = -1e30f;
  #pragma unroll
  for (int jj=0;jj<4;++jj){
    int j = tid + (jj<<8);
    const float* kr = kbase + (size_t)j*32;
    float s = 0.f;
    #pragma unroll
    for (int d=0;d<32;++d) s = fmaf(qs[d], kr[d], s);
    s = s*SCALEV + relbase[(size_t)j*8];
    sv[jj]=s; lmax = fmaxf(lmax, s);
  }
  #pragma unroll
  for (int o=32;o;o>>=1) lmax = fmaxf(lmax, __shfl_xor(lmax,o));
  if ((tid&63)==0) rb1[tid>>6]=lmax;
  __syncthreads();
  float mx = fmaxf(fmaxf(rb1[0],rb1[1]),fmaxf(rb1[2],rb1[3]));
  float lsum = 0.f;
  #pragma unroll
  for (int jj=0;jj<4;++jj){
    float e = expf(sv[jj]-mx);
    probs[tid+(jj<<8)] = e; lsum += e;
  }
  #pragma unroll
  for (int o=32;o;o>>=1) lsum += __shfl_xor(lsum,o);
  if ((tid&63)==0) rb2[tid>>6]=lsum;
  __syncthreads();
  float inv = 1.0f/(rb2[0]+rb2[1]+rb2[2]+rb2[3]);
  // PV: thread (jl, d)
  int d = tid & 31, jl = tid >> 5;
  float acc = 0.f;
  for (int j=jl; j<1024; j+=8) acc = fmaf(probs[j], vbase[(size_t)j*32+d], acc);
  red[tid] = acc;
  __syncthreads();
  if (tid < 32){
    float s2 = 0.f;
    #pragma unroll
    for (int w=0;w<8;++w) s2 += red[(w<<5)+tid];
    out[((((size_t)(b<<10)+i))<<8) + (h<<5) + tid] = s2*inv;  // (B,N,256)
  }
}

// ------------- generic GEMM: 8 rows/block staged in LDS ---------------------
// EPI: 0 = none, 1 = +bias+resid, 2 = gelu(+bias)
template<int K, int NC, int EPI>
__global__ __launch_bounds__(256) void gemm8(const float* __restrict__ A,
    const float* __restrict__ W, const float* __restrict__ bias,
    const float* __restrict__ resid, float* __restrict__ out){
  __shared__ __align__(16) float sA[8*K];
  int tid = threadIdx.x;
  int row0 = blockIdx.y*8;
  const float* Ab = A + (size_t)row0*K;
  for (int t=tid; t<8*K; t+=256) sA[t]=Ab[t];
  __syncthreads();
  int col = blockIdx.x*256 + tid;
  const float* w = W + col;
  float acc[8];
  #pragma unroll
  for (int r=0;r<8;++r) acc[r]=0.f;
  for (int k=0;k<K;k+=4){
    float wv0 = w[(size_t)k*NC];
    float wv1 = w[(size_t)(k+1)*NC];
    float wv2 = w[(size_t)(k+2)*NC];
    float wv3 = w[(size_t)(k+3)*NC];
    #pragma unroll
    for (int r=0;r<8;++r){
      float4 a4 = *(const float4*)&sA[r*K+k];
      acc[r] = fmaf(a4.x,wv0,acc[r]);
      acc[r] = fmaf(a4.y,wv1,acc[r]);
      acc[r] = fmaf(a4.z,wv2,acc[r]);
      acc[r] = fmaf(a4.w,wv3,acc[r]);
    }
  }
  float bv = (EPI!=0) ? bias[col] : 0.f;
  #pragma unroll
  for (int r=0;r<8;++r){
    size_t o = (size_t)(row0+r)*NC + col;
    float vv = acc[r];
    if (EPI==1) vv = vv + bv + resid[o];
    else if (EPI==2) vv = gelu_f(vv+bv);
    out[o]=vv;
  }
}

extern "C" void kernel_launch(void* const* d_in, const int* in_sizes, int n_in,
                              void* d_out, int out_size, void* d_ws, size_t ws_size,
                              hipStream_t stream){
  const float* x_in  = (const float*)d_in[0];
  const float* coords= (const float*)d_in[1];
  const float* vel   = (const float*)d_in[2];
  const float* ln1_g = (const float*)d_in[3];
  const float* ln1_b = (const float*)d_in[4];
  const float* Wqkv  = (const float*)d_in[5];
  const float* relW1 = (const float*)d_in[6];
  const float* relb1 = (const float*)d_in[7];
  const float* relW2 = (const float*)d_in[8];
  const float* relb2 = (const float*)d_in[9];
  const float* Wout  = (const float*)d_in[10];
  const float* bout  = (const float*)d_in[11];
  const float* ln2_g = (const float*)d_in[12];
  const float* ln2_b = (const float*)d_in[13];
  const float* Wf1   = (const float*)d_in[14];
  const float* bf1   = (const float*)d_in[15];
  const float* Wf2   = (const float*)d_in[16];
  const float* bf2   = (const float*)d_in[17];

  float* x  = (float*)d_out;                 // residual stream lives in d_out
  float* ws = (float*)d_ws;
  float* h    = ws;                          // 2048*256
  float* qkv  = h    + 524288;               // 2048*768
  float* q    = qkv  + 1572864;              // 2*8*1024*32
  float* k    = q    + 524288;
  float* v    = k    + 524288;
  float* att  = v    + 524288;               // 2048*256
  float* mid  = att  + 524288;               // 2048*1024
  float* rel  = mid  + 2097152;              // 2*1024*1024*8
  float* sint = rel  + 16777216;             // 1024*16
  float* cost = sint + 16384;

  hipMemcpyAsync(x, x_in, sizeof(float)*524288, hipMemcpyDeviceToDevice, stream);
  rope_table<<<64,256,0,stream>>>(sint,cost);

  for (int l=0;l<2;++l){
    ln_kernel<<<2048,256,0,stream>>>(x, ln1_g+l*256, ln1_b+l*256, h);
    gemm8<256,768,0><<<dim3(3,256),256,0,stream>>>(h, Wqkv+(size_t)l*196608, nullptr, nullptr, qkv);
    rope_apply<<<2048,256,0,stream>>>(qkv, sint, cost, q, k, v);
    rel_kernel<<<8192,256,0,stream>>>(coords, vel, relW1+l*320, relb1+l*64,
                                      relW2+l*512, relb2+l*8, rel);
    attn_kernel<<<16384,256,0,stream>>>(q, k, v, rel, att);
    gemm8<256,256,1><<<dim3(1,256),256,0,stream>>>(att, Wout+(size_t)l*65536, bout+l*256, x, x);
    ln_kernel<<<2048,256,0,stream>>>(x, ln2_g+l*256, ln2_b+l*256, h);
    gemm8<256,1024,2><<<dim3(4,256),256,0,stream>>>(h, Wf1+(size_t)l*262144, bf1+l*1024, nullptr, mid);
    gemm8<1024,256,1><<<dim3(1,256),256,0,stream>>>(mid, Wf2+(size_t)l*262144, bf2+l*256, x, x);
  }
}

// Round 2
// 615.894 us; speedup vs baseline: 2.5794x; 2.5794x over previous
//
#include <hip/hip_runtime.h>
#include <math.h>

#define BN 2
#define NN 1024
#define DDIM 256
#define HH 8
#define HDIM 32
#define FFD 1024
#define EPSV 1e-5f
#define SCALEV 0.17677669529663687f
#define ITILE 32
#define JTILE 64

__device__ __forceinline__ float gelu_f(float x){
  return 0.5f*x*(1.0f+erff(x*0.70710678118654752f));
}

// ---------------- LayerNorm: one block per row (256 threads, D=256) ----------
__global__ __launch_bounds__(256) void ln_kernel(const float* __restrict__ x,
    const float* __restrict__ g, const float* __restrict__ b, float* __restrict__ out){
  int row = blockIdx.x, tid = threadIdx.x;
  float val = x[(size_t)row*DDIM + tid];
  float s = val;
  #pragma unroll
  for (int o=32;o;o>>=1) s += __shfl_xor(s,o);
  __shared__ float sb[4], sb2[4];
  if ((tid&63)==0) sb[tid>>6]=s;
  __syncthreads();
  float mean = (sb[0]+sb[1]+sb[2]+sb[3]) * (1.0f/DDIM);
  float d = val-mean;
  float vs = d*d;
  #pragma unroll
  for (int o=32;o;o>>=1) vs += __shfl_xor(vs,o);
  if ((tid&63)==0) sb2[tid>>6]=vs;
  __syncthreads();
  float var = (sb2[0]+sb2[1]+sb2[2]+sb2[3]) * (1.0f/DDIM);
  out[(size_t)row*DDIM + tid] = d*rsqrtf(var+EPSV)*g[tid]+b[tid];
}

// ---------------- RoPE tables ------------------------------------------------
__global__ __launch_bounds__(256) void rope_table(float* __restrict__ sint, float* __restrict__ cost){
  int idx = blockIdx.x*256+threadIdx.x;   // 16384
  int i = idx >> 4, d = idx & 15;
  float freq = (float)i * powf(10000.0f, -(float)d/16.0f);
  sint[idx]=sinf(freq); cost[idx]=cosf(freq);
}

// ------------- split qkv + rope; writes q,k,v in (B,H,N,HD) -----------------
__global__ __launch_bounds__(256) void rope_apply(const float* __restrict__ qkv,
    const float* __restrict__ sint, const float* __restrict__ cost,
    float* __restrict__ q, float* __restrict__ k, float* __restrict__ v){
  int row = blockIdx.x;                 // b*1024 + i
  int b = row>>10, i = row&1023;
  int tid = threadIdx.x; int h = tid>>5, d = tid&31;
  const float* base = qkv + (size_t)row*768;
  size_t oidx = (((size_t)(b*HH+h)*NN) + i)*HDIM + d;
  v[oidx] = base[512 + h*32 + d];
  int dd = (d<16) ? d : d-16;
  float s = sint[i*16+dd], c = cost[i*16+dd];
  float q1 = base[h*32+dd], q2 = base[h*32+dd+16];
  q[oidx] = (d<16) ? (q1*c - q2*s) : (q2*c + q1*s);
  float k1 = base[256+h*32+dd], k2 = base[256+h*32+dd+16];
  k[oidx] = (d<16) ? (k1*c - k2*s) : (k2*c + k1*s);
}

// ------------- rel bias MLP: thread per (b,i,j); writes (B,H,N,N) -----------
__global__ __launch_bounds__(256) void rel_kernel(const float* __restrict__ coords,
    const float* __restrict__ vel, const float* __restrict__ W1, const float* __restrict__ b1,
    const float* __restrict__ W2, const float* __restrict__ b2, float* __restrict__ rel){
  __shared__ float sW1[320], sW2[512], sb1[64], sb2[8];
  int tid = threadIdx.x;
  sW2[tid]=W2[tid]; sW2[tid+256]=W2[tid+256];
  if (tid<256) sW1[tid]=W1[tid];
  if (tid<64)  sW1[256+tid]=W1[256+tid];
  if (tid<64)  sb1[tid]=b1[tid];
  if (tid<8)   sb2[tid]=b2[tid];
  __syncthreads();
  size_t idx = (size_t)blockIdx.x*256 + tid;   // < 2*1024*1024
  int j = idx & 1023; int i = (int)((idx>>10)&1023); int b = (int)(idx>>20);
  const float* ci = coords + ((size_t)(b<<10)+i)*2;
  const float* cj = coords + ((size_t)(b<<10)+j)*2;
  const float* vi = vel    + ((size_t)(b<<10)+i)*2;
  const float* vj = vel    + ((size_t)(b<<10)+j)*2;
  float f0 = ci[0]-cj[0], f1 = ci[1]-cj[1];
  float f2 = sqrtf(f0*f0+f1*f1);
  float f3 = vi[0]-vj[0], f4 = vi[1]-vj[1];
  float o[8];
  #pragma unroll
  for (int hh=0;hh<8;++hh) o[hh]=sb2[hh];
  for (int r=0;r<64;++r){
    float t = sb1[r] + f0*sW1[r] + f1*sW1[64+r] + f2*sW1[128+r]
                     + f3*sW1[192+r] + f4*sW1[256+r];
    float gl = gelu_f(t);
    #pragma unroll
    for (int hh=0;hh<8;++hh) o[hh] = fmaf(gl, sW2[r*8+hh], o[hh]);
  }
  // layout (B,H,N,N): rel[((b*8+h)<<20) + (i<<10) + j]
  size_t base_out = ((size_t)b<<23) + ((size_t)i<<10) + j;
  #pragma unroll
  for (int hh=0;hh<8;++hh) rel[base_out + ((size_t)hh<<20)] = o[hh];
}

// ------------- flash-style attention: block per (b,h,itile of 32) -----------
__global__ __launch_bounds__(256) void attn_fused(const float* __restrict__ q,
    const float* __restrict__ kk, const float* __restrict__ vv,
    const float* __restrict__ rel, float* __restrict__ out){
  int bh    = blockIdx.x >> 5;     // b*8+h
  int itile = blockIdx.x & 31;
  int i0 = itile * ITILE;
  int tid = threadIdx.x;

  __shared__ __align__(16) float ktile[JTILE*32];
  __shared__ __align__(16) float vtile[JTILE*32];
  __shared__ float stile[ITILE*65];
  __shared__ float pmax[8*32];
  __shared__ float psum[8*32];

  int iq = tid & 31, jg = tid >> 5;   // QK role
  int ip = tid >> 3, dg = tid & 7;    // PV role

  float4 qv[8];
  const float* qrow = q + ((size_t)((bh<<10) + i0 + iq))*32;
  #pragma unroll
  for (int u=0; u<8; ++u) qv[u] = ((const float4*)qrow)[u];

  const float* kbase = kk + ((size_t)bh<<15);
  const float* vbase = vv + ((size_t)bh<<15);
  const float* relrow = rel + ((size_t)bh<<20) + ((size_t)(i0+iq)<<10);

  float m_qk = -1e30f;
  float m_pv = -1e30f;
  float l_pv = 0.f;
  float o0=0.f,o1=0.f,o2=0.f,o3=0.f;

  for (int t=0; t<16; ++t){
    int j0 = t*JTILE;
    __syncthreads();
    {
      const float4* kg = (const float4*)(kbase + (size_t)j0*32);
      const float4* vg = (const float4*)(vbase + (size_t)j0*32);
      float4* ks = (float4*)ktile; float4* vs = (float4*)vtile;
      ks[tid] = kg[tid]; ks[tid+256] = kg[tid+256];
      vs[tid] = vg[tid]; vs[tid+256] = vg[tid+256];
    }
    __syncthreads();
    float sv[8]; float lmax = -1e30f;
    float4 r4a = ((const float4*)(relrow + j0 + jg*8))[0];
    float4 r4b = ((const float4*)(relrow + j0 + jg*8))[1];
    float relv[8] = {r4a.x,r4a.y,r4a.z,r4a.w,r4b.x,r4b.y,r4b.z,r4b.w};
    #pragma unroll
    for (int jj=0; jj<8; ++jj){
      const float4* kr = (const float4*)(ktile + (jg*8+jj)*32);
      float s = 0.f;
      #pragma unroll
      for (int u=0; u<8; ++u){
        float4 kv = kr[u];
        s = fmaf(qv[u].x, kv.x, s); s = fmaf(qv[u].y, kv.y, s);
        s = fmaf(qv[u].z, kv.z, s); s = fmaf(qv[u].w, kv.w, s);
      }
      s = fmaf(s, SCALEV, relv[jj]);
      sv[jj] = s; lmax = fmaxf(lmax, s);
    }
    pmax[jg*32 + iq] = lmax;
    __syncthreads();
    float mq = m_qk, mp = m_pv;
    #pragma unroll
    for (int g=0; g<8; ++g){
      mq = fmaxf(mq, pmax[g*32 + iq]);
      mp = fmaxf(mp, pmax[g*32 + ip]);
    }
    float ls = 0.f;
    #pragma unroll
    for (int jj=0; jj<8; ++jj){
      float p = __expf(sv[jj] - mq);
      stile[iq*65 + jg*8 + jj] = p;
      ls += p;
    }
    psum[jg*32 + iq] = ls;
    m_qk = mq;
    float scale = __expf(m_pv - mp);    // first iter: exp(-1e30-mp) = 0
    m_pv = mp;
    o0*=scale; o1*=scale; o2*=scale; o3*=scale;
    __syncthreads();
    float ts = 0.f;
    #pragma unroll
    for (int g=0; g<8; ++g) ts += psum[g*32 + ip];
    l_pv = l_pv*scale + ts;
    #pragma unroll 8
    for (int j=0; j<JTILE; ++j){
      float p = stile[ip*65 + j];
      const float4 vvv = *((const float4*)(vtile + j*32 + dg*4));
      o0 = fmaf(p, vvv.x, o0); o1 = fmaf(p, vvv.y, o1);
      o2 = fmaf(p, vvv.z, o2); o3 = fmaf(p, vvv.w, o3);
    }
  }
  int b = bh>>3, h = bh&7;
  float invl = 1.0f/l_pv;
  float4 ov; ov.x=o0*invl; ov.y=o1*invl; ov.z=o2*invl; ov.w=o3*invl;
  *((float4*)(out + (((size_t)((b<<10) + i0 + ip))<<8) + h*32 + dg*4)) = ov;
}

// ------------- generic GEMM: R rows/block staged in LDS ---------------------
// EPI: 0 = none, 1 = +bias+resid, 2 = gelu(+bias)
template<int K, int NC, int EPI, int R>
__global__ __launch_bounds__(256) void gemm8(const float* __restrict__ A,
    const float* __restrict__ W, const float* __restrict__ bias,
    const float* __restrict__ resid, float* __restrict__ out){
  __shared__ __align__(16) float sA[R*K];
  int tid = threadIdx.x;
  int row0 = blockIdx.y*R;
  const float* Ab = A + (size_t)row0*K;
  for (int t=tid; t<R*K; t+=256) sA[t]=Ab[t];
  __syncthreads();
  int col = blockIdx.x*256 + tid;
  const float* w = W + col;
  float acc[R];
  #pragma unroll
  for (int r=0;r<R;++r) acc[r]=0.f;
  for (int k=0;k<K;k+=4){
    float wv0 = w[(size_t)k*NC];
    float wv1 = w[(size_t)(k+1)*NC];
    float wv2 = w[(size_t)(k+2)*NC];
    float wv3 = w[(size_t)(k+3)*NC];
    #pragma unroll
    for (int r=0;r<R;++r){
      float4 a4 = *(const float4*)&sA[r*K+k];
      acc[r] = fmaf(a4.x,wv0,acc[r]);
      acc[r] = fmaf(a4.y,wv1,acc[r]);
      acc[r] = fmaf(a4.z,wv2,acc[r]);
      acc[r] = fmaf(a4.w,wv3,acc[r]);
    }
  }
  float bv = (EPI!=0) ? bias[col] : 0.f;
  #pragma unroll
  for (int r=0;r<R;++r){
    size_t o = (size_t)(row0+r)*NC + col;
    float vv = acc[r];
    if (EPI==1) vv = vv + bv + resid[o];
    else if (EPI==2) vv = gelu_f(vv+bv);
    out[o]=vv;
  }
}

extern "C" void kernel_launch(void* const* d_in, const int* in_sizes, int n_in,
                              void* d_out, int out_size, void* d_ws, size_t ws_size,
                              hipStream_t stream){
  const float* x_in  = (const float*)d_in[0];
  const float* coords= (const float*)d_in[1];
  const float* vel   = (const float*)d_in[2];
  const float* ln1_g = (const float*)d_in[3];
  const float* ln1_b = (const float*)d_in[4];
  const float* Wqkv  = (const float*)d_in[5];
  const float* relW1 = (const float*)d_in[6];
  const float* relb1 = (const float*)d_in[7];
  const float* relW2 = (const float*)d_in[8];
  const float* relb2 = (const float*)d_in[9];
  const float* Wout  = (const float*)d_in[10];
  const float* bout  = (const float*)d_in[11];
  const float* ln2_g = (const float*)d_in[12];
  const float* ln2_b = (const float*)d_in[13];
  const float* Wf1   = (const float*)d_in[14];
  const float* bf1   = (const float*)d_in[15];
  const float* Wf2   = (const float*)d_in[16];
  const float* bf2   = (const float*)d_in[17];

  float* x  = (float*)d_out;
  float* ws = (float*)d_ws;
  float* h    = ws;                          // 2048*256
  float* qkv  = h    + 524288;               // 2048*768
  float* q    = qkv  + 1572864;              // 2*8*1024*32
  float* k    = q    + 524288;
  float* v    = k    + 524288;
  float* att  = v    + 524288;               // 2048*256
  float* mid  = att  + 524288;               // 2048*1024
  float* rel  = mid  + 2097152;              // 2*8*1024*1024 (B,H,N,N)
  float* sint = rel  + 16777216;             // 1024*16
  float* cost = sint + 16384;

  hipMemcpyAsync(x, x_in, sizeof(float)*524288, hipMemcpyDeviceToDevice, stream);
  rope_table<<<64,256,0,stream>>>(sint,cost);

  for (int l=0;l<2;++l){
    ln_kernel<<<2048,256,0,stream>>>(x, ln1_g+l*256, ln1_b+l*256, h);
    gemm8<256,768,0,16><<<dim3(3,128),256,0,stream>>>(h, Wqkv+(size_t)l*196608, nullptr, nullptr, qkv);
    rope_apply<<<2048,256,0,stream>>>(qkv, sint, cost, q, k, v);
    rel_kernel<<<8192,256,0,stream>>>(coords, vel, relW1+l*320, relb1+l*64,
                                      relW2+l*512, relb2+l*8, rel);
    attn_fused<<<512,256,0,stream>>>(q, k, v, rel, att);
    gemm8<256,256,1,8><<<dim3(1,256),256,0,stream>>>(att, Wout+(size_t)l*65536, bout+l*256, x, x);
    ln_kernel<<<2048,256,0,stream>>>(x, ln2_g+l*256, ln2_b+l*256, h);
    gemm8<256,1024,2,16><<<dim3(4,128),256,0,stream>>>(h, Wf1+(size_t)l*262144, bf1+l*1024, nullptr, mid);
    gemm8<1024,256,1,8><<<dim3(1,256),256,0,stream>>>(mid, Wf2+(size_t)l*262144, bf2+l*256, x, x);
  }
}

// Round 3
// 544.120 us; speedup vs baseline: 2.9196x; 1.1319x over previous
//
#include <hip/hip_runtime.h>
#include <math.h>

#define BN 2
#define NN 1024
#define DDIM 256
#define HH 8
#define HDIM 32
#define FFD 1024
#define EPSV 1e-5f
#define SCALEV 0.17677669529663687f
#define ITILE 32
#define JTILE 64

__device__ __forceinline__ float gelu_f(float x){
  return 0.5f*x*(1.0f+erff(x*0.70710678118654752f));
}
__device__ __forceinline__ float gelu_fast(float x){
  // x * sigmoid(1.702x); |x| is small here (<~1) so approx err < 2e-3
  return x * __builtin_amdgcn_rcpf(1.0f + __expf(-1.702f*x));
}
__device__ __forceinline__ unsigned int pack_bf16(float lo, float hi){
  unsigned int ul = __float_as_uint(lo), uh = __float_as_uint(hi);
  ul += 0x7fff + ((ul>>16)&1);
  uh += 0x7fff + ((uh>>16)&1);
  return (ul>>16) | (uh & 0xffff0000u);
}
__device__ __forceinline__ float bflo(unsigned int u){ return __uint_as_float(u<<16); }
__device__ __forceinline__ float bfhi(unsigned int u){ return __uint_as_float(u & 0xffff0000u); }

// ---------------- LayerNorm ----------
__global__ __launch_bounds__(256) void ln_kernel(const float* __restrict__ x,
    const float* __restrict__ g, const float* __restrict__ b, float* __restrict__ out){
  int row = blockIdx.x, tid = threadIdx.x;
  float val = x[(size_t)row*DDIM + tid];
  float s = val;
  #pragma unroll
  for (int o=32;o;o>>=1) s += __shfl_xor(s,o);
  __shared__ float sb[4], sb2[4];
  if ((tid&63)==0) sb[tid>>6]=s;
  __syncthreads();
  float mean = (sb[0]+sb[1]+sb[2]+sb[3]) * (1.0f/DDIM);
  float d = val-mean;
  float vs = d*d;
  #pragma unroll
  for (int o=32;o;o>>=1) vs += __shfl_xor(vs,o);
  if ((tid&63)==0) sb2[tid>>6]=vs;
  __syncthreads();
  float var = (sb2[0]+sb2[1]+sb2[2]+sb2[3]) * (1.0f/DDIM);
  out[(size_t)row*DDIM + tid] = d*rsqrtf(var+EPSV)*g[tid]+b[tid];
}

// ---------------- RoPE tables -------------------------------------------------
__global__ __launch_bounds__(256) void rope_table(float* __restrict__ sint, float* __restrict__ cost){
  int idx = blockIdx.x*256+threadIdx.x;   // 16384
  int i = idx >> 4, d = idx & 15;
  float freq = (float)i * powf(10000.0f, -(float)d/16.0f);
  sint[idx]=sinf(freq); cost[idx]=cosf(freq);
}

// ------------- split qkv + rope -----------------------------------------------
__global__ __launch_bounds__(256) void rope_apply(const float* __restrict__ qkv,
    const float* __restrict__ sint, const float* __restrict__ cost,
    float* __restrict__ q, float* __restrict__ k, float* __restrict__ v){
  int row = blockIdx.x;                 // b*1024 + i
  int b = row>>10, i = row&1023;
  int tid = threadIdx.x; int h = tid>>5, d = tid&31;
  const float* base = qkv + (size_t)row*768;
  size_t oidx = (((size_t)(b*HH+h)*NN) + i)*HDIM + d;
  v[oidx] = base[512 + h*32 + d];
  int dd = (d<16) ? d : d-16;
  float s = sint[i*16+dd], c = cost[i*16+dd];
  float q1 = base[h*32+dd], q2 = base[h*32+dd+16];
  q[oidx] = (d<16) ? (q1*c - q2*s) : (q2*c + q1*s);
  float k1 = base[256+h*32+dd], k2 = base[256+h*32+dd+16];
  k[oidx] = (d<16) ? (k1*c - k2*s) : (k2*c + k1*s);
}

// ------------- rel precompute: separable parts per node -----------------------
// A[node][64] = b1[r] + c0*W1[0,r] + c1*W1[1,r] + v0*W1[3,r] + v1*W1[4,r]
// BT[r][2048] = same without b1
__global__ __launch_bounds__(256) void rel_pre(const float* __restrict__ coords,
    const float* __restrict__ vel, const float* __restrict__ W1,
    const float* __restrict__ b1, float* __restrict__ A, float* __restrict__ BT){
  int gid = blockIdx.x*256 + threadIdx.x;  // 2048*64
  int node = gid >> 6, r = gid & 63;
  float c0 = coords[node*2], c1 = coords[node*2+1];
  float v0 = vel[node*2],    v1 = vel[node*2+1];
  float bv = c0*W1[r] + c1*W1[64+r] + v0*W1[192+r] + v1*W1[256+r];
  A[gid] = b1[r] + bv;
  BT[r*2048 + node] = bv;
}

// ------------- rel bias MLP: thread per (b,i,2j); writes bf16 (B,H,N,N) -------
__global__ __launch_bounds__(256) void rel_kernel2(const float* __restrict__ coords,
    const float* __restrict__ vel, const float* __restrict__ A,
    const float* __restrict__ BT, const float* __restrict__ W1,
    const float* __restrict__ W2, const float* __restrict__ b2,
    unsigned int* __restrict__ relbf){
  int bid = blockIdx.x;                  // 4096 = b*1024*2
  int b  = bid >> 11;
  int i  = (bid >> 1) & 1023;
  int jh = bid & 1;
  int tid = threadIdx.x;
  int j0 = jh*512 + tid*2;
  int nodei = (b<<10) + i;
  int nodej = (b<<10) + j0;
  const float* Ai = A + (size_t)nodei*64;        // block-uniform -> s_load
  const float* Wd = W1 + 128;                    // uniform
  float4 cj = *(const float4*)(coords + (size_t)nodej*2);
  float ci0 = coords[nodei*2], ci1 = coords[nodei*2+1];
  float dx0 = ci0-cj.x, dy0 = ci1-cj.y;
  float dx1 = ci0-cj.z, dy1 = ci1-cj.w;
  float d0 = sqrtf(dx0*dx0+dy0*dy0);
  float d1 = sqrtf(dx1*dx1+dy1*dy1);
  float o0[8], o1[8];
  #pragma unroll
  for (int hh=0;hh<8;++hh){ float bb=b2[hh]; o0[hh]=bb; o1[hh]=bb; }
  const float* btb = BT + nodej;
  #pragma unroll 8
  for (int r=0;r<64;++r){
    float2 bt = *(const float2*)(btb + (size_t)r*2048);
    float a = Ai[r], wd = Wd[r];
    float t0 = fmaf(d0, wd, a - bt.x);
    float t1 = fmaf(d1, wd, a - bt.y);
    float g0 = gelu_fast(t0);
    float g1 = gelu_fast(t1);
    #pragma unroll
    for (int hh=0;hh<8;++hh){
      float w = W2[r*8+hh];
      o0[hh] = fmaf(g0, w, o0[hh]);
      o1[hh] = fmaf(g1, w, o1[hh]);
    }
  }
  // bf16 index: ((b*8+hh)<<20) + (i<<10) + j0 ; store packed pair as uint
  unsigned int ubase = ((unsigned)(b*8)<<19) + ((unsigned)i<<9) + (j0>>1);
  #pragma unroll
  for (int hh=0;hh<8;++hh)
    relbf[ubase + ((unsigned)hh<<19)] = pack_bf16(o0[hh], o1[hh]);
}

// ------------- flash-style attention: block per (b,h,itile of 32) -------------
__global__ __launch_bounds__(256) void attn_fused(const float* __restrict__ q,
    const float* __restrict__ kk, const float* __restrict__ vv,
    const unsigned int* __restrict__ relbf, float* __restrict__ out){
  int bh    = blockIdx.x >> 5;     // b*8+h
  int itile = blockIdx.x & 31;
  int i0 = itile * ITILE;
  int tid = threadIdx.x;

  __shared__ __align__(16) float ktile[JTILE*32];
  __shared__ __align__(16) float vtile[JTILE*32];
  __shared__ float stile[ITILE*65];
  __shared__ float pmax[8*32];
  __shared__ float psum[8*32];

  int iq = tid & 31, jg = tid >> 5;   // QK role
  int ip = tid >> 3, dg = tid & 7;    // PV role

  float4 qv[8];
  const float* qrow = q + ((size_t)((bh<<10) + i0 + iq))*32;
  #pragma unroll
  for (int u=0; u<8; ++u) qv[u] = ((const float4*)qrow)[u];

  const float* kbase = kk + ((size_t)bh<<15);
  const float* vbase = vv + ((size_t)bh<<15);
  // bf16 rel row: ((bh)<<20) + ((i0+iq)<<10) elements; as uint index >>1
  const unsigned int* relrow = relbf + (((size_t)bh<<19)) + ((size_t)(i0+iq)<<9);

  float m_qk = -1e30f;
  float m_pv = -1e30f;
  float l_pv = 0.f;
  float o0=0.f,o1=0.f,o2=0.f,o3=0.f;

  for (int t=0; t<16; ++t){
    int j0 = t*JTILE;
    __syncthreads();
    {
      const float4* kg = (const float4*)(kbase + (size_t)j0*32);
      const float4* vg = (const float4*)(vbase + (size_t)j0*32);
      float4* ks = (float4*)ktile; float4* vs = (float4*)vtile;
      ks[tid] = kg[tid]; ks[tid+256] = kg[tid+256];
      vs[tid] = vg[tid]; vs[tid+256] = vg[tid+256];
    }
    __syncthreads();
    float sv[8]; float lmax = -1e30f;
    uint4 ru = *(const uint4*)(relrow + ((j0 + jg*8)>>1));
    float relv[8] = {bflo(ru.x),bfhi(ru.x),bflo(ru.y),bfhi(ru.y),
                     bflo(ru.z),bfhi(ru.z),bflo(ru.w),bfhi(ru.w)};
    #pragma unroll
    for (int jj=0; jj<8; ++jj){
      const float4* kr = (const float4*)(ktile + (jg*8+jj)*32);
      float s = 0.f;
      #pragma unroll
      for (int u=0; u<8; ++u){
        float4 kv = kr[u];
        s = fmaf(qv[u].x, kv.x, s); s = fmaf(qv[u].y, kv.y, s);
        s = fmaf(qv[u].z, kv.z, s); s = fmaf(qv[u].w, kv.w, s);
      }
      s = fmaf(s, SCALEV, relv[jj]);
      sv[jj] = s; lmax = fmaxf(lmax, s);
    }
    pmax[jg*32 + iq] = lmax;
    __syncthreads();
    float mq = m_qk, mp = m_pv;
    #pragma unroll
    for (int g=0; g<8; ++g){
      mq = fmaxf(mq, pmax[g*32 + iq]);
      mp = fmaxf(mp, pmax[g*32 + ip]);
    }
    float ls = 0.f;
    #pragma unroll
    for (int jj=0; jj<8; ++jj){
      float p = __expf(sv[jj] - mq);
      stile[iq*65 + jg*8 + jj] = p;
      ls += p;
    }
    psum[jg*32 + iq] = ls;
    m_qk = mq;
    float scale = __expf(m_pv - mp);
    m_pv = mp;
    o0*=scale; o1*=scale; o2*=scale; o3*=scale;
    __syncthreads();
    float ts = 0.f;
    #pragma unroll
    for (int g=0; g<8; ++g) ts += psum[g*32 + ip];
    l_pv = l_pv*scale + ts;
    #pragma unroll 8
    for (int j=0; j<JTILE; ++j){
      float p = stile[ip*65 + j];
      const float4 vvv = *((const float4*)(vtile + j*32 + dg*4));
      o0 = fmaf(p, vvv.x, o0); o1 = fmaf(p, vvv.y, o1);
      o2 = fmaf(p, vvv.z, o2); o3 = fmaf(p, vvv.w, o3);
    }
  }
  int b = bh>>3, h = bh&7;
  float invl = 1.0f/l_pv;
  float4 ov; ov.x=o0*invl; ov.y=o1*invl; ov.z=o2*invl; ov.w=o3*invl;
  *((float4*)(out + (((size_t)((b<<10) + i0 + ip))<<8) + h*32 + dg*4)) = ov;
}

// ------------- generic GEMM: R rows/block staged in LDS -----------------------
template<int K, int NC, int EPI, int R>
__global__ __launch_bounds__(256) void gemm8(const float* __restrict__ A,
    const float* __restrict__ W, const float* __restrict__ bias,
    const float* __restrict__ resid, float* __restrict__ out){
  __shared__ __align__(16) float sA[R*K];
  int tid = threadIdx.x;
  int row0 = blockIdx.y*R;
  const float* Ab = A + (size_t)row0*K;
  for (int t=tid; t<R*K; t+=256) sA[t]=Ab[t];
  __syncthreads();
  int col = blockIdx.x*256 + tid;
  const float* w = W + col;
  float acc[R];
  #pragma unroll
  for (int r=0;r<R;++r) acc[r]=0.f;
  for (int k=0;k<K;k+=4){
    float wv0 = w[(size_t)k*NC];
    float wv1 = w[(size_t)(k+1)*NC];
    float wv2 = w[(size_t)(k+2)*NC];
    float wv3 = w[(size_t)(k+3)*NC];
    #pragma unroll
    for (int r=0;r<R;++r){
      float4 a4 = *(const float4*)&sA[r*K+k];
      acc[r] = fmaf(a4.x,wv0,acc[r]);
      acc[r] = fmaf(a4.y,wv1,acc[r]);
      acc[r] = fmaf(a4.z,wv2,acc[r]);
      acc[r] = fmaf(a4.w,wv3,acc[r]);
    }
  }
  float bv = (EPI!=0) ? bias[col] : 0.f;
  #pragma unroll
  for (int r=0;r<R;++r){
    size_t o = (size_t)(row0+r)*NC + col;
    float vv = acc[r];
    if (EPI==1) vv = vv + bv + resid[o];
    else if (EPI==2) vv = gelu_f(vv+bv);
    out[o]=vv;
  }
}

extern "C" void kernel_launch(void* const* d_in, const int* in_sizes, int n_in,
                              void* d_out, int out_size, void* d_ws, size_t ws_size,
                              hipStream_t stream){
  const float* x_in  = (const float*)d_in[0];
  const float* coords= (const float*)d_in[1];
  const float* vel   = (const float*)d_in[2];
  const float* ln1_g = (const float*)d_in[3];
  const float* ln1_b = (const float*)d_in[4];
  const float* Wqkv  = (const float*)d_in[5];
  const float* relW1 = (const float*)d_in[6];
  const float* relb1 = (const float*)d_in[7];
  const float* relW2 = (const float*)d_in[8];
  const float* relb2 = (const float*)d_in[9];
  const float* Wout  = (const float*)d_in[10];
  const float* bout  = (const float*)d_in[11];
  const float* ln2_g = (const float*)d_in[12];
  const float* ln2_b = (const float*)d_in[13];
  const float* Wf1   = (const float*)d_in[14];
  const float* bf1   = (const float*)d_in[15];
  const float* Wf2   = (const float*)d_in[16];
  const float* bf2   = (const float*)d_in[17];

  float* x  = (float*)d_out;
  float* ws = (float*)d_ws;
  float* h    = ws;                          // 2048*256
  float* qkv  = h    + 524288;               // 2048*768
  float* q    = qkv  + 1572864;
  float* k    = q    + 524288;
  float* v    = k    + 524288;
  float* att  = v    + 524288;               // 2048*256
  float* mid  = att  + 524288;               // 2048*1024
  float* A    = mid  + 2097152;              // 2048*64
  float* BT   = A    + 131072;               // 64*2048
  float* sint = BT   + 131072;               // 1024*16
  float* cost = sint + 16384;
  unsigned int* relbf = (unsigned int*)(cost + 16384);  // 2*8*1024*1024 bf16 = 8M uints

  hipMemcpyAsync(x, x_in, sizeof(float)*524288, hipMemcpyDeviceToDevice, stream);
  rope_table<<<64,256,0,stream>>>(sint,cost);

  for (int l=0;l<2;++l){
    ln_kernel<<<2048,256,0,stream>>>(x, ln1_g+l*256, ln1_b+l*256, h);
    gemm8<256,768,0,16><<<dim3(3,128),256,0,stream>>>(h, Wqkv+(size_t)l*196608, nullptr, nullptr, qkv);
    rope_apply<<<2048,256,0,stream>>>(qkv, sint, cost, q, k, v);
    rel_pre<<<512,256,0,stream>>>(coords, vel, relW1+l*320, relb1+l*64, A, BT);
    rel_kernel2<<<4096,256,0,stream>>>(coords, vel, A, BT, relW1+l*320,
                                       relW2+l*512, relb2+l*8, relbf);
    attn_fused<<<512,256,0,stream>>>(q, k, v, relbf, att);
    gemm8<256,256,1,8><<<dim3(1,256),256,0,stream>>>(att, Wout+(size_t)l*65536, bout+l*256, x, x);
    ln_kernel<<<2048,256,0,stream>>>(x, ln2_g+l*256, ln2_b+l*256, h);
    gemm8<256,1024,2,16><<<dim3(4,128),256,0,stream>>>(h, Wf1+(size_t)l*262144, bf1+l*1024, nullptr, mid);
    gemm8<1024,256,1,8><<<dim3(1,256),256,0,stream>>>(mid, Wf2+(size_t)l*262144, bf2+l*256, x, x);
  }
}

// Round 4
// 493.216 us; speedup vs baseline: 3.2209x; 1.1032x over previous
//
#include <hip/hip_runtime.h>
#include <math.h>

#define BN 2
#define NN 1024
#define DDIM 256
#define HH 8
#define HDIM 32
#define FFD 1024
#define EPSV 1e-5f
#define SCALEV 0.17677669529663687f
#define LPAD 72

typedef __attribute__((ext_vector_type(8))) short s16x8;
typedef __attribute__((ext_vector_type(4))) float f32x4;

__device__ __forceinline__ float gelu_f(float x){
  return 0.5f*x*(1.0f+erff(x*0.70710678118654752f));
}
__device__ __forceinline__ float gelu_fast(float x){
  return x * __builtin_amdgcn_rcpf(1.0f + __expf(-1.702f*x));
}
__device__ __forceinline__ unsigned int pack_bf16(float lo, float hi){
  unsigned int ul = __float_as_uint(lo), uh = __float_as_uint(hi);
  ul += 0x7fff + ((ul>>16)&1);
  uh += 0x7fff + ((uh>>16)&1);
  return (ul>>16) | (uh & 0xffff0000u);
}
__device__ __forceinline__ unsigned short f2bf(float x){
  unsigned int u = __float_as_uint(x);
  u += 0x7fff + ((u>>16)&1);
  return (unsigned short)(u>>16);
}
__device__ __forceinline__ float bf2f(unsigned short u){
  return __uint_as_float(((unsigned int)u)<<16);
}
__device__ __forceinline__ s16x8 pack8(float4 a, float4 b){
  s16x8 r;
  r[0]=(short)f2bf(a.x); r[1]=(short)f2bf(a.y); r[2]=(short)f2bf(a.z); r[3]=(short)f2bf(a.w);
  r[4]=(short)f2bf(b.x); r[5]=(short)f2bf(b.y); r[6]=(short)f2bf(b.z); r[7]=(short)f2bf(b.w);
  return r;
}
__device__ __forceinline__ f32x4 mfma16(s16x8 a, s16x8 b, f32x4 c){
  return __builtin_amdgcn_mfma_f32_16x16x32_bf16(a,b,c,0,0,0);
}

// ---------------- LayerNorm ----------
__global__ __launch_bounds__(256) void ln_kernel(const float* __restrict__ x,
    const float* __restrict__ g, const float* __restrict__ b, float* __restrict__ out){
  int row = blockIdx.x, tid = threadIdx.x;
  float val = x[(size_t)row*DDIM + tid];
  float s = val;
  #pragma unroll
  for (int o=32;o;o>>=1) s += __shfl_xor(s,o);
  __shared__ float sb[4], sb2[4];
  if ((tid&63)==0) sb[tid>>6]=s;
  __syncthreads();
  float mean = (sb[0]+sb[1]+sb[2]+sb[3]) * (1.0f/DDIM);
  float d = val-mean;
  float vs = d*d;
  #pragma unroll
  for (int o=32;o;o>>=1) vs += __shfl_xor(vs,o);
  if ((tid&63)==0) sb2[tid>>6]=vs;
  __syncthreads();
  float var = (sb2[0]+sb2[1]+sb2[2]+sb2[3]) * (1.0f/DDIM);
  out[(size_t)row*DDIM + tid] = d*rsqrtf(var+EPSV)*g[tid]+b[tid];
}

// ---------------- RoPE tables -------------------------------------------------
__global__ __launch_bounds__(256) void rope_table(float* __restrict__ sint, float* __restrict__ cost){
  int idx = blockIdx.x*256+threadIdx.x;   // 16384
  int i = idx >> 4, d = idx & 15;
  float freq = (float)i * powf(10000.0f, -(float)d/16.0f);
  sint[idx]=sinf(freq); cost[idx]=cosf(freq);
}

// ------------- split qkv + rope -----------------------------------------------
__global__ __launch_bounds__(256) void rope_apply(const float* __restrict__ qkv,
    const float* __restrict__ sint, const float* __restrict__ cost,
    float* __restrict__ q, float* __restrict__ k, float* __restrict__ v){
  int row = blockIdx.x;                 // b*1024 + i
  int b = row>>10, i = row&1023;
  int tid = threadIdx.x; int h = tid>>5, d = tid&31;
  const float* base = qkv + (size_t)row*768;
  size_t oidx = (((size_t)(b*HH+h)*NN) + i)*HDIM + d;
  v[oidx] = base[512 + h*32 + d];
  int dd = (d<16) ? d : d-16;
  float s = sint[i*16+dd], c = cost[i*16+dd];
  float q1 = base[h*32+dd], q2 = base[h*32+dd+16];
  q[oidx] = (d<16) ? (q1*c - q2*s) : (q2*c + q1*s);
  float k1 = base[256+h*32+dd], k2 = base[256+h*32+dd+16];
  k[oidx] = (d<16) ? (k1*c - k2*s) : (k2*c + k1*s);
}

// ------------- rel precompute: separable parts per node -----------------------
__global__ __launch_bounds__(256) void rel_pre(const float* __restrict__ coords,
    const float* __restrict__ vel, const float* __restrict__ W1,
    const float* __restrict__ b1, float* __restrict__ A, float* __restrict__ BT){
  int gid = blockIdx.x*256 + threadIdx.x;  // 2048*64
  int node = gid >> 6, r = gid & 63;
  float c0 = coords[node*2], c1 = coords[node*2+1];
  float v0 = vel[node*2],    v1 = vel[node*2+1];
  float bv = c0*W1[r] + c1*W1[64+r] + v0*W1[192+r] + v1*W1[256+r];
  A[gid] = b1[r] + bv;
  BT[r*2048 + node] = bv;
}

// ------------- rel bias MLP: thread per (b,i,2j); writes bf16 (B,H,N,N) -------
__global__ __launch_bounds__(256) void rel_kernel2(const float* __restrict__ coords,
    const float* __restrict__ vel, const float* __restrict__ A,
    const float* __restrict__ BT, const float* __restrict__ W1,
    const float* __restrict__ W2, const float* __restrict__ b2,
    unsigned int* __restrict__ relbf){
  int bid = blockIdx.x;                  // 4096 = b*1024*2
  int b  = bid >> 11;
  int i  = (bid >> 1) & 1023;
  int jh = bid & 1;
  int tid = threadIdx.x;
  int j0 = jh*512 + tid*2;
  int nodei = (b<<10) + i;
  int nodej = (b<<10) + j0;
  const float* Ai = A + (size_t)nodei*64;
  const float* Wd = W1 + 128;
  float4 cj = *(const float4*)(coords + (size_t)nodej*2);
  float ci0 = coords[nodei*2], ci1 = coords[nodei*2+1];
  float dx0 = ci0-cj.x, dy0 = ci1-cj.y;
  float dx1 = ci0-cj.z, dy1 = ci1-cj.w;
  float d0 = sqrtf(dx0*dx0+dy0*dy0);
  float d1 = sqrtf(dx1*dx1+dy1*dy1);
  float o0[8], o1[8];
  #pragma unroll
  for (int hh=0;hh<8;++hh){ float bb=b2[hh]; o0[hh]=bb; o1[hh]=bb; }
  const float* btb = BT + nodej;
  #pragma unroll 8
  for (int r=0;r<64;++r){
    float2 bt = *(const float2*)(btb + (size_t)r*2048);
    float a = Ai[r], wd = Wd[r];
    float t0 = fmaf(d0, wd, a - bt.x);
    float t1 = fmaf(d1, wd, a - bt.y);
    float g0 = gelu_fast(t0);
    float g1 = gelu_fast(t1);
    #pragma unroll
    for (int hh=0;hh<8;++hh){
      float w = W2[r*8+hh];
      o0[hh] = fmaf(g0, w, o0[hh]);
      o1[hh] = fmaf(g1, w, o1[hh]);
    }
  }
  unsigned int ubase = ((unsigned)(b*8)<<19) + ((unsigned)i<<9) + (j0>>1);
  #pragma unroll
  for (int hh=0;hh<8;++hh)
    relbf[ubase + ((unsigned)hh<<19)] = pack_bf16(o0[hh], o1[hh]);
}

// ------------- MFMA flash attention: block = (b,h, 32-row i-tile) -------------
// 4 waves: wave w computes S chunks (j-quarter w, both 16-row i-halves) and
// PV output chunk (i-half w>>1, d-half w&1). 16x16x32 bf16 MFMA.
__global__ __launch_bounds__(256) void attn_mfma(
    const float* __restrict__ q, const float* __restrict__ kk,
    const float* __restrict__ vv, const unsigned short* __restrict__ relbf,
    float* __restrict__ out){
  int bh = blockIdx.x >> 5;
  int i0 = (blockIdx.x & 31) * 32;
  int tid = threadIdx.x;
  int w  = tid >> 6;
  int l  = tid & 63;
  int lc = l & 15;
  int lg = l >> 4;

  __shared__ __align__(16) unsigned short VT[2][32*LPAD];
  __shared__ __align__(16) unsigned short PL[2][32*LPAD];
  __shared__ __align__(16) float wmaxs[2][32][4];
  __shared__ __align__(16) float wsums[2][32][4];
  __shared__ float mld[2][32];
  __shared__ float lld[2][32];

  const float* qb = q + ((size_t)(bh<<10) + i0)*32;
  const float* kb = kk + ((size_t)bh<<15);
  const float* vb = vv + ((size_t)bh<<15);
  const unsigned short* relb = relbf + ((size_t)bh<<20) + ((size_t)i0<<10);

  // Q fragments, SCALE folded in. A-layout: m=l&15, k=(l>>4)*8+j
  const float* qr0 = qb + (size_t)(lc)*32 + lg*8;
  const float* qr1 = qb + (size_t)(16 + lc)*32 + lg*8;
  float4 qa0 = ((const float4*)qr0)[0], qb0 = ((const float4*)qr0)[1];
  float4 qa1 = ((const float4*)qr1)[0], qb1 = ((const float4*)qr1)[1];
  qa0.x*=SCALEV; qa0.y*=SCALEV; qa0.z*=SCALEV; qa0.w*=SCALEV;
  qb0.x*=SCALEV; qb0.y*=SCALEV; qb0.z*=SCALEV; qb0.w*=SCALEV;
  qa1.x*=SCALEV; qa1.y*=SCALEV; qa1.z*=SCALEV; qa1.w*=SCALEV;
  qb1.x*=SCALEV; qb1.y*=SCALEV; qb1.z*=SCALEV; qb1.w*=SCALEV;
  s16x8 qf0 = pack8(qa0, qb0);
  s16x8 qf1 = pack8(qa1, qb1);

  if (tid < 32){ mld[0][tid] = -1e30f; lld[0][tid] = 0.f; }

  f32x4 acc; acc[0]=0.f; acc[1]=0.f; acc[2]=0.f; acc[3]=0.f;
  const int dh  = w & 1;
  const int pih = w >> 1;

  for (int t=0; t<16; ++t){
    const int c = t & 1, nx = c ^ 1;
    const int j0 = t*64;
    // ---- Phase A: stage V^T, compute S = QK^T + rel, per-wave row-max ----
    {
      int jj = tid & 63, d0 = (tid >> 6)*8;
      const float* vr = vb + (size_t)(j0+jj)*32 + d0;
      float4 v0 = ((const float4*)vr)[0];
      float4 v1 = ((const float4*)vr)[1];
      unsigned short* dst = VT[c];
      dst[(d0+0)*LPAD+jj]=f2bf(v0.x); dst[(d0+1)*LPAD+jj]=f2bf(v0.y);
      dst[(d0+2)*LPAD+jj]=f2bf(v0.z); dst[(d0+3)*LPAD+jj]=f2bf(v0.w);
      dst[(d0+4)*LPAD+jj]=f2bf(v1.x); dst[(d0+5)*LPAD+jj]=f2bf(v1.y);
      dst[(d0+6)*LPAD+jj]=f2bf(v1.z); dst[(d0+7)*LPAD+jj]=f2bf(v1.w);
    }
    // K B-fragment from global: n=l&15 -> j, k=(l>>4)*8 -> d
    const float* kr = kb + (size_t)(j0 + w*16 + lc)*32 + lg*8;
    s16x8 kf = pack8(((const float4*)kr)[0], ((const float4*)kr)[1]);
    f32x4 z; z[0]=0.f; z[1]=0.f; z[2]=0.f; z[3]=0.f;
    f32x4 s0 = mfma16(qf0, kf, z);
    f32x4 s1 = mfma16(qf1, kf, z);
    float sv0[4], sv1[4], rm0[4], rm1[4];
    const int jc = j0 + w*16 + lc;
    #pragma unroll
    for (int r=0;r<4;++r){
      int row0 = lg*4 + r;
      sv0[r] = s0[r] + bf2f(relb[(size_t)row0*1024 + jc]);
      sv1[r] = s1[r] + bf2f(relb[(size_t)(row0+16)*1024 + jc]);
      float a0 = sv0[r], a1 = sv1[r];
      #pragma unroll
      for (int o=1;o<16;o<<=1){
        a0 = fmaxf(a0, __shfl_xor(a0,o));
        a1 = fmaxf(a1, __shfl_xor(a1,o));
      }
      rm0[r]=a0; rm1[r]=a1;
    }
    if (lc == 0){
      #pragma unroll
      for (int r=0;r<4;++r){
        wmaxs[c][lg*4+r][w]    = rm0[r];
        wmaxs[c][lg*4+r+16][w] = rm1[r];
      }
    }
    __syncthreads();
    // ---- Phase B: new max, P=exp, row-sums, P->LDS bf16, rescale acc ----
    float mn0[4], mn1[4], sc0[4], sc1[4];
    #pragma unroll
    for (int r=0;r<4;++r){
      int row0 = lg*4+r;
      float4 wm0 = *(const float4*)wmaxs[c][row0];
      float4 wm1 = *(const float4*)wmaxs[c][row0+16];
      float mo0 = mld[c][row0], mo1 = mld[c][row0+16];
      float t0 = fmaxf(fmaxf(wm0.x,wm0.y), fmaxf(wm0.z,wm0.w));
      float t1 = fmaxf(fmaxf(wm1.x,wm1.y), fmaxf(wm1.z,wm1.w));
      mn0[r] = fmaxf(mo0, t0);  mn1[r] = fmaxf(mo1, t1);
      sc0[r] = __expf(mo0 - mn0[r]); sc1[r] = __expf(mo1 - mn1[r]);
    }
    float ps0[4], ps1[4];
    #pragma unroll
    for (int r=0;r<4;++r){
      int row0 = lg*4+r;
      float p0 = __expf(sv0[r]-mn0[r]);
      float p1 = __expf(sv1[r]-mn1[r]);
      PL[c][(size_t)row0*LPAD + w*16 + lc]      = f2bf(p0);
      PL[c][(size_t)(row0+16)*LPAD + w*16 + lc] = f2bf(p1);
      #pragma unroll
      for (int o=1;o<16;o<<=1){
        p0 += __shfl_xor(p0,o);
        p1 += __shfl_xor(p1,o);
      }
      ps0[r]=p0; ps1[r]=p1;
    }
    if (lc == 0){
      #pragma unroll
      for (int r=0;r<4;++r){
        wsums[c][lg*4+r][w]    = ps0[r];
        wsums[c][lg*4+r+16][w] = ps1[r];
      }
    }
    #pragma unroll
    for (int r=0;r<4;++r){
      float s = (pih==0) ? sc0[r] : sc1[r];
      acc[r] *= s;
    }
    __syncthreads();
    // ---- Phase C: PV MFMA; wave 0 updates running m,l (ping-pong) ----
    #pragma unroll
    for (int kc=0;kc<2;++kc){
      s16x8 pa = *(const s16x8*)&PL[c][(size_t)(pih*16 + lc)*LPAD + kc*32 + lg*8];
      s16x8 vf = *(const s16x8*)&VT[c][(size_t)(dh*16 + lc)*LPAD + kc*32 + lg*8];
      acc = mfma16(pa, vf, acc);
    }
    if (w==0 && lc==0){
      #pragma unroll
      for (int r=0;r<4;++r){
        int row0 = lg*4+r;
        float4 u0 = *(const float4*)wsums[c][row0];
        float4 u1 = *(const float4*)wsums[c][row0+16];
        lld[nx][row0]    = lld[c][row0]*sc0[r]    + (u0.x+u0.y+u0.z+u0.w);
        lld[nx][row0+16] = lld[c][row0+16]*sc1[r] + (u1.x+u1.y+u1.z+u1.w);
        mld[nx][row0]    = mn0[r];
        mld[nx][row0+16] = mn1[r];
      }
    }
  }
  __syncthreads();
  int b = bh>>3, hh = bh&7;
  #pragma unroll
  for (int r=0;r<4;++r){
    int row = pih*16 + lg*4 + r;
    float li = lld[0][row];
    out[((size_t)((b<<10)+i0+row))*256 + hh*32 + dh*16 + lc] = acc[r]/li;
  }
}

// ------------- generic GEMM: R rows/block staged in LDS -----------------------
template<int K, int NC, int EPI, int R>
__global__ __launch_bounds__(256) void gemm8(const float* __restrict__ A,
    const float* __restrict__ W, const float* __restrict__ bias,
    const float* __restrict__ resid, float* __restrict__ out){
  __shared__ __align__(16) float sA[R*K];
  int tid = threadIdx.x;
  int row0 = blockIdx.y*R;
  const float* Ab = A + (size_t)row0*K;
  for (int t=tid; t<R*K; t+=256) sA[t]=Ab[t];
  __syncthreads();
  int col = blockIdx.x*256 + tid;
  const float* w = W + col;
  float acc[R];
  #pragma unroll
  for (int r=0;r<R;++r) acc[r]=0.f;
  for (int k=0;k<K;k+=4){
    float wv0 = w[(size_t)k*NC];
    float wv1 = w[(size_t)(k+1)*NC];
    float wv2 = w[(size_t)(k+2)*NC];
    float wv3 = w[(size_t)(k+3)*NC];
    #pragma unroll
    for (int r=0;r<R;++r){
      float4 a4 = *(const float4*)&sA[r*K+k];
      acc[r] = fmaf(a4.x,wv0,acc[r]);
      acc[r] = fmaf(a4.y,wv1,acc[r]);
      acc[r] = fmaf(a4.z,wv2,acc[r]);
      acc[r] = fmaf(a4.w,wv3,acc[r]);
    }
  }
  float bv = (EPI!=0) ? bias[col] : 0.f;
  #pragma unroll
  for (int r=0;r<R;++r){
    size_t o = (size_t)(row0+r)*NC + col;
    float vv = acc[r];
    if (EPI==1) vv = vv + bv + resid[o];
    else if (EPI==2) vv = gelu_f(vv+bv);
    out[o]=vv;
  }
}

extern "C" void kernel_launch(void* const* d_in, const int* in_sizes, int n_in,
                              void* d_out, int out_size, void* d_ws, size_t ws_size,
                              hipStream_t stream){
  const float* x_in  = (const float*)d_in[0];
  const float* coords= (const float*)d_in[1];
  const float* vel   = (const float*)d_in[2];
  const float* ln1_g = (const float*)d_in[3];
  const float* ln1_b = (const float*)d_in[4];
  const float* Wqkv  = (const float*)d_in[5];
  const float* relW1 = (const float*)d_in[6];
  const float* relb1 = (const float*)d_in[7];
  const float* relW2 = (const float*)d_in[8];
  const float* relb2 = (const float*)d_in[9];
  const float* Wout  = (const float*)d_in[10];
  const float* bout  = (const float*)d_in[11];
  const float* ln2_g = (const float*)d_in[12];
  const float* ln2_b = (const float*)d_in[13];
  const float* Wf1   = (const float*)d_in[14];
  const float* bf1   = (const float*)d_in[15];
  const float* Wf2   = (const float*)d_in[16];
  const float* bf2   = (const float*)d_in[17];

  float* x  = (float*)d_out;
  float* ws = (float*)d_ws;
  float* h    = ws;                          // 2048*256
  float* qkv  = h    + 524288;               // 2048*768
  float* q    = qkv  + 1572864;
  float* k    = q    + 524288;
  float* v    = k    + 524288;
  float* att  = v    + 524288;               // 2048*256
  float* mid  = att  + 524288;               // 2048*1024
  float* A    = mid  + 2097152;              // 2048*64
  float* BT   = A    + 131072;               // 64*2048
  float* sint = BT   + 131072;               // 1024*16
  float* cost = sint + 16384;
  unsigned int* relbf = (unsigned int*)(cost + 16384);  // 2*8*1024*1024 bf16

  hipMemcpyAsync(x, x_in, sizeof(float)*524288, hipMemcpyDeviceToDevice, stream);
  rope_table<<<64,256,0,stream>>>(sint,cost);

  for (int l=0;l<2;++l){
    ln_kernel<<<2048,256,0,stream>>>(x, ln1_g+l*256, ln1_b+l*256, h);
    gemm8<256,768,0,16><<<dim3(3,128),256,0,stream>>>(h, Wqkv+(size_t)l*196608, nullptr, nullptr, qkv);
    rope_apply<<<2048,256,0,stream>>>(qkv, sint, cost, q, k, v);
    rel_pre<<<512,256,0,stream>>>(coords, vel, relW1+l*320, relb1+l*64, A, BT);
    rel_kernel2<<<4096,256,0,stream>>>(coords, vel, A, BT, relW1+l*320,
                                       relW2+l*512, relb2+l*8, relbf);
    attn_mfma<<<512,256,0,stream>>>(q, k, v, (const unsigned short*)relbf, att);
    gemm8<256,256,1,8><<<dim3(1,256),256,0,stream>>>(att, Wout+(size_t)l*65536, bout+l*256, x, x);
    ln_kernel<<<2048,256,0,stream>>>(x, ln2_g+l*256, ln2_b+l*256, h);
    gemm8<256,1024,2,16><<<dim3(4,128),256,0,stream>>>(h, Wf1+(size_t)l*262144, bf1+l*1024, nullptr, mid);
    gemm8<1024,256,1,8><<<dim3(1,256),256,0,stream>>>(mid, Wf2+(size_t)l*262144, bf2+l*256, x, x);
  }
}

// Round 5
// 309.924 us; speedup vs baseline: 5.1258x; 1.5914x over previous
//
#include <hip/hip_runtime.h>
#include <math.h>

#define BN_ 2
#define NN 1024
#define DDIM 256
#define HH 8
#define HDIM 32
#define FFD 1024
#define EPSV 1e-5f
#define SCALEV 0.17677669529663687f
#define LPAD 72

typedef __attribute__((ext_vector_type(8))) short s16x8;
typedef __attribute__((ext_vector_type(4))) float f32x4;

__device__ __forceinline__ float gelu_f(float x){
  return 0.5f*x*(1.0f+erff(x*0.70710678118654752f));
}
__device__ __forceinline__ float gelu_fast(float x){
  return x * __builtin_amdgcn_rcpf(1.0f + __expf(-1.702f*x));
}
__device__ __forceinline__ unsigned int pack_bf16(float lo, float hi){
  unsigned int ul = __float_as_uint(lo), uh = __float_as_uint(hi);
  ul += 0x7fff + ((ul>>16)&1);
  uh += 0x7fff + ((uh>>16)&1);
  return (ul>>16) | (uh & 0xffff0000u);
}
__device__ __forceinline__ unsigned short f2bf(float x){
  unsigned int u = __float_as_uint(x);
  u += 0x7fff + ((u>>16)&1);
  return (unsigned short)(u>>16);
}
__device__ __forceinline__ float bf2f(unsigned short u){
  return __uint_as_float(((unsigned int)u)<<16);
}
__device__ __forceinline__ f32x4 mfma16(s16x8 a, s16x8 b, f32x4 c){
  return __builtin_amdgcn_mfma_f32_16x16x32_bf16(a,b,c,0,0,0);
}

// ---------------- LayerNorm: f32 in, bf16 out --------------------------------
__global__ __launch_bounds__(256) void ln_kernel(const float* __restrict__ x,
    const float* __restrict__ g, const float* __restrict__ b,
    unsigned short* __restrict__ out){
  int row = blockIdx.x, tid = threadIdx.x;
  float val = x[(size_t)row*DDIM + tid];
  float s = val;
  #pragma unroll
  for (int o=32;o;o>>=1) s += __shfl_xor(s,o);
  __shared__ float sb[4], sb2[4];
  if ((tid&63)==0) sb[tid>>6]=s;
  __syncthreads();
  float mean = (sb[0]+sb[1]+sb[2]+sb[3]) * (1.0f/DDIM);
  float d = val-mean;
  float vs = d*d;
  #pragma unroll
  for (int o=32;o;o>>=1) vs += __shfl_xor(vs,o);
  if ((tid&63)==0) sb2[tid>>6]=vs;
  __syncthreads();
  float var = (sb2[0]+sb2[1]+sb2[2]+sb2[3]) * (1.0f/DDIM);
  out[(size_t)row*DDIM + tid] = f2bf(d*rsqrtf(var+EPSV)*g[tid]+b[tid]);
}

// ---------------- RoPE tables -------------------------------------------------
__global__ __launch_bounds__(256) void rope_table(float* __restrict__ sint, float* __restrict__ cost){
  int idx = blockIdx.x*256+threadIdx.x;   // 16384
  int i = idx >> 4, d = idx & 15;
  float freq = (float)i * powf(10000.0f, -(float)d/16.0f);
  sint[idx]=sinf(freq); cost[idx]=cosf(freq);
}

// ---------------- weight convert+transpose f32(K,NC) -> bf16 WT(NC,K) --------
// scaleCols: columns n < scaleCols get multiplied by scaleVal (Q-scale fold)
__global__ __launch_bounds__(256) void wt_convert(const float* __restrict__ in,
    unsigned short* __restrict__ out, int K, int NC, int scaleCols, float scaleVal){
  __shared__ float tile[32][33];
  int tn0 = blockIdx.x*32;
  int tk0 = blockIdx.y*32;
  size_t loff = (size_t)blockIdx.z * K * NC;
  int t = threadIdx.x;
  int col = t & 31, rr = t >> 5;
  #pragma unroll
  for (int i=0;i<4;++i){
    int row = rr + i*8;
    tile[row][col] = in[loff + (size_t)(tk0+row)*NC + tn0+col];
  }
  __syncthreads();
  #pragma unroll
  for (int i=0;i<4;++i){
    int row = rr + i*8;
    int n = tn0 + row;
    float s = (n < scaleCols) ? scaleVal : 1.0f;
    out[loff + (size_t)n*K + tk0 + col] = f2bf(tile[col][row]*s);
  }
}

// ------------- split qkv + rope (bf16 in/out) --------------------------------
__global__ __launch_bounds__(256) void rope_apply_bf(const unsigned short* __restrict__ qkv,
    const float* __restrict__ sint, const float* __restrict__ cost,
    unsigned short* __restrict__ q, unsigned short* __restrict__ k,
    unsigned short* __restrict__ v){
  int row = blockIdx.x;                 // b*1024 + i
  int b = row>>10, i = row&1023;
  int tid = threadIdx.x; int h = tid>>5, d = tid&31;
  const unsigned short* base = qkv + (size_t)row*768;
  size_t oidx = (((size_t)((b<<3)+h)<<10) + i)*32 + d;
  v[oidx] = base[512 + h*32 + d];
  int dd = (d<16) ? d : d-16;
  float s = sint[i*16+dd], c = cost[i*16+dd];
  float q1 = bf2f(base[h*32+dd]), q2 = bf2f(base[h*32+dd+16]);
  q[oidx] = f2bf((d<16) ? (q1*c - q2*s) : (q2*c + q1*s));
  float k1 = bf2f(base[256+h*32+dd]), k2 = bf2f(base[256+h*32+dd+16]);
  k[oidx] = f2bf((d<16) ? (k1*c - k2*s) : (k2*c + k1*s));
}

// ------------- rel precompute: separable parts per node -----------------------
__global__ __launch_bounds__(256) void rel_pre(const float* __restrict__ coords,
    const float* __restrict__ vel, const float* __restrict__ W1,
    const float* __restrict__ b1, float* __restrict__ A, float* __restrict__ BT){
  int gid = blockIdx.x*256 + threadIdx.x;  // 2048*64
  int node = gid >> 6, r = gid & 63;
  float c0 = coords[node*2], c1 = coords[node*2+1];
  float v0 = vel[node*2],    v1 = vel[node*2+1];
  float bv = c0*W1[r] + c1*W1[64+r] + v0*W1[192+r] + v1*W1[256+r];
  A[gid] = b1[r] + bv;
  BT[r*2048 + node] = bv;
}

// ------------- rel bias MLP: thread per (b,i,2j); writes bf16 (B,H,N,N) -------
__global__ __launch_bounds__(256) void rel_kernel2(const float* __restrict__ coords,
    const float* __restrict__ vel, const float* __restrict__ A,
    const float* __restrict__ BT, const float* __restrict__ W1,
    const float* __restrict__ W2, const float* __restrict__ b2,
    unsigned int* __restrict__ relbf){
  int bid = blockIdx.x;                  // 4096 = b*1024*2
  int b  = bid >> 11;
  int i  = (bid >> 1) & 1023;
  int jh = bid & 1;
  int tid = threadIdx.x;
  int j0 = jh*512 + tid*2;
  int nodei = (b<<10) + i;
  int nodej = (b<<10) + j0;
  const float* Ai = A + (size_t)nodei*64;
  const float* Wd = W1 + 128;
  float4 cj = *(const float4*)(coords + (size_t)nodej*2);
  float ci0 = coords[nodei*2], ci1 = coords[nodei*2+1];
  float dx0 = ci0-cj.x, dy0 = ci1-cj.y;
  float dx1 = ci0-cj.z, dy1 = ci1-cj.w;
  float d0 = sqrtf(dx0*dx0+dy0*dy0);
  float d1 = sqrtf(dx1*dx1+dy1*dy1);
  float o0[8], o1[8];
  #pragma unroll
  for (int hh=0;hh<8;++hh){ float bb=b2[hh]; o0[hh]=bb; o1[hh]=bb; }
  const float* btb = BT + nodej;
  #pragma unroll 8
  for (int r=0;r<64;++r){
    float2 bt = *(const float2*)(btb + (size_t)r*2048);
    float a = Ai[r], wd = Wd[r];
    float t0 = fmaf(d0, wd, a - bt.x);
    float t1 = fmaf(d1, wd, a - bt.y);
    float g0 = gelu_fast(t0);
    float g1 = gelu_fast(t1);
    #pragma unroll
    for (int hh=0;hh<8;++hh){
      float w = W2[r*8+hh];
      o0[hh] = fmaf(g0, w, o0[hh]);
      o1[hh] = fmaf(g1, w, o1[hh]);
    }
  }
  unsigned int ubase = ((unsigned)(b*8)<<19) + ((unsigned)i<<9) + (j0>>1);
  #pragma unroll
  for (int hh=0;hh<8;++hh)
    relbf[ubase + ((unsigned)hh<<19)] = pack_bf16(o0[hh], o1[hh]);
}

// ------------- MFMA flash attention (all-bf16 inputs) -------------------------
__global__ __launch_bounds__(256) void attn_mfma(
    const unsigned short* __restrict__ q, const unsigned short* __restrict__ kk,
    const unsigned short* __restrict__ vv, const unsigned short* __restrict__ relbf,
    unsigned short* __restrict__ out){
  int bh = blockIdx.x >> 5;
  int i0 = (blockIdx.x & 31) * 32;
  int tid = threadIdx.x;
  int w  = tid >> 6;
  int l  = tid & 63;
  int lc = l & 15;
  int lg = l >> 4;

  __shared__ __align__(16) unsigned short VT[2][32*LPAD];
  __shared__ __align__(16) unsigned short PL[2][32*LPAD];
  __shared__ __align__(16) float wmaxs[2][32][4];
  __shared__ __align__(16) float wsums[2][32][4];
  __shared__ float mld[2][32];
  __shared__ float lld[2][32];

  const unsigned short* qb = q + ((size_t)(bh<<10) + i0)*32;
  const unsigned short* kb = kk + ((size_t)bh<<15);
  const unsigned short* vb = vv + ((size_t)bh<<15);
  const unsigned short* relb = relbf + ((size_t)bh<<20) + ((size_t)i0<<10);

  // Q fragments (scale pre-folded into Wqkv). A-layout: m=l&15, k=(l>>4)*8+j
  s16x8 qf0 = *(const s16x8*)(qb + (size_t)lc*32 + lg*8);
  s16x8 qf1 = *(const s16x8*)(qb + (size_t)(16+lc)*32 + lg*8);

  if (tid < 32){ mld[0][tid] = -1e30f; lld[0][tid] = 0.f; }

  f32x4 acc; acc[0]=0.f; acc[1]=0.f; acc[2]=0.f; acc[3]=0.f;
  const int dh  = w & 1;
  const int pih = w >> 1;

  for (int t=0; t<16; ++t){
    const int c = t & 1, nx = c ^ 1;
    const int j0 = t*64;
    // ---- Phase A: stage V^T, compute S = QK^T + rel, per-wave row-max ----
    {
      int jj = tid & 63, d0 = (tid >> 6)*8;
      s16x8 v8 = *(const s16x8*)(vb + (size_t)(j0+jj)*32 + d0);
      unsigned short* dst = VT[c];
      #pragma unroll
      for (int e=0;e<8;++e) dst[(d0+e)*LPAD + jj] = (unsigned short)v8[e];
    }
    s16x8 kf = *(const s16x8*)(kb + (size_t)(j0 + w*16 + lc)*32 + lg*8);
    f32x4 z; z[0]=0.f; z[1]=0.f; z[2]=0.f; z[3]=0.f;
    f32x4 s0 = mfma16(qf0, kf, z);
    f32x4 s1 = mfma16(qf1, kf, z);
    float sv0[4], sv1[4], rm0[4], rm1[4];
    const int jc = j0 + w*16 + lc;
    #pragma unroll
    for (int r=0;r<4;++r){
      int row0 = lg*4 + r;
      sv0[r] = s0[r] + bf2f(relb[(size_t)row0*1024 + jc]);
      sv1[r] = s1[r] + bf2f(relb[(size_t)(row0+16)*1024 + jc]);
      float a0 = sv0[r], a1 = sv1[r];
      #pragma unroll
      for (int o=1;o<16;o<<=1){
        a0 = fmaxf(a0, __shfl_xor(a0,o));
        a1 = fmaxf(a1, __shfl_xor(a1,o));
      }
      rm0[r]=a0; rm1[r]=a1;
    }
    if (lc == 0){
      #pragma unroll
      for (int r=0;r<4;++r){
        wmaxs[c][lg*4+r][w]    = rm0[r];
        wmaxs[c][lg*4+r+16][w] = rm1[r];
      }
    }
    __syncthreads();
    // ---- Phase B: new max, P=exp, row-sums, P->LDS bf16, rescale acc ----
    float mn0[4], mn1[4], sc0[4], sc1[4];
    #pragma unroll
    for (int r=0;r<4;++r){
      int row0 = lg*4+r;
      float4 wm0 = *(const float4*)wmaxs[c][row0];
      float4 wm1 = *(const float4*)wmaxs[c][row0+16];
      float mo0 = mld[c][row0], mo1 = mld[c][row0+16];
      float t0 = fmaxf(fmaxf(wm0.x,wm0.y), fmaxf(wm0.z,wm0.w));
      float t1 = fmaxf(fmaxf(wm1.x,wm1.y), fmaxf(wm1.z,wm1.w));
      mn0[r] = fmaxf(mo0, t0);  mn1[r] = fmaxf(mo1, t1);
      sc0[r] = __expf(mo0 - mn0[r]); sc1[r] = __expf(mo1 - mn1[r]);
    }
    float ps0[4], ps1[4];
    #pragma unroll
    for (int r=0;r<4;++r){
      int row0 = lg*4+r;
      float p0 = __expf(sv0[r]-mn0[r]);
      float p1 = __expf(sv1[r]-mn1[r]);
      PL[c][(size_t)row0*LPAD + w*16 + lc]      = f2bf(p0);
      PL[c][(size_t)(row0+16)*LPAD + w*16 + lc] = f2bf(p1);
      #pragma unroll
      for (int o=1;o<16;o<<=1){
        p0 += __shfl_xor(p0,o);
        p1 += __shfl_xor(p1,o);
      }
      ps0[r]=p0; ps1[r]=p1;
    }
    if (lc == 0){
      #pragma unroll
      for (int r=0;r<4;++r){
        wsums[c][lg*4+r][w]    = ps0[r];
        wsums[c][lg*4+r+16][w] = ps1[r];
      }
    }
    #pragma unroll
    for (int r=0;r<4;++r){
      float s = (pih==0) ? sc0[r] : sc1[r];
      acc[r] *= s;
    }
    __syncthreads();
    // ---- Phase C: PV MFMA; wave 0 updates running m,l (ping-pong) ----
    #pragma unroll
    for (int kc=0;kc<2;++kc){
      s16x8 pa = *(const s16x8*)&PL[c][(size_t)(pih*16 + lc)*LPAD + kc*32 + lg*8];
      s16x8 vf = *(const s16x8*)&VT[c][(size_t)(dh*16 + lc)*LPAD + kc*32 + lg*8];
      acc = mfma16(pa, vf, acc);
    }
    if (w==0 && lc==0){
      #pragma unroll
      for (int r=0;r<4;++r){
        int row0 = lg*4+r;
        float4 u0 = *(const float4*)wsums[c][row0];
        float4 u1 = *(const float4*)wsums[c][row0+16];
        lld[nx][row0]    = lld[c][row0]*sc0[r]    + (u0.x+u0.y+u0.z+u0.w);
        lld[nx][row0+16] = lld[c][row0+16]*sc1[r] + (u1.x+u1.y+u1.z+u1.w);
        mld[nx][row0]    = mn0[r];
        mld[nx][row0+16] = mn1[r];
      }
    }
  }
  __syncthreads();
  int b = bh>>3, hh = bh&7;
  #pragma unroll
  for (int r=0;r<4;++r){
    int row = pih*16 + lg*4 + r;
    float li = lld[0][row];
    out[((size_t)((b<<10)+i0+row))*256 + hh*32 + dh*16 + lc] = f2bf(acc[r]/li);
  }
}

// ------------- MFMA GEMM: C[M,NC] = A[M,K] @ W[K,NC], A bf16, WT bf16(NC,K) --
// EPI: 0 = none (bf16 out), 1 = +bias+resid (f32 out), 2 = gelu(+bias) (bf16 out)
template<int K, int NC, int EPI, int BM, int BNt>
__global__ __launch_bounds__(256) void gemm_mfma(
    const unsigned short* __restrict__ Aa, const unsigned short* __restrict__ WT,
    const float* __restrict__ bias, const float* __restrict__ resid,
    void* __restrict__ outv){
  constexpr int WMm = BM/2, WNn = BNt/2;
  constexpr int FM = WMm/16, FN = WNn/16;
  constexpr int LP = 40;
  __shared__ __align__(16) unsigned short As[BM*LP];
  __shared__ __align__(16) unsigned short Bs[BNt*LP];
  const int tid = threadIdx.x;
  const int w = tid>>6, l = tid&63, lc = l&15, lg = l>>4;
  const int wm = w&1, wn = w>>1;
  const int n0 = blockIdx.x*BNt, m0 = blockIdx.y*BM;
  f32x4 acc[FM][FN];
  #pragma unroll
  for (int a=0;a<FM;++a)
    #pragma unroll
    for (int c=0;c<FN;++c){ acc[a][c][0]=0.f; acc[a][c][1]=0.f; acc[a][c][2]=0.f; acc[a][c][3]=0.f; }

  for (int k0=0; k0<K; k0+=32){
    __syncthreads();
    if constexpr (BM==64){
      int row = tid>>2, cg = tid&3;
      *(s16x8*)&As[row*LP+cg*8] = *(const s16x8*)&Aa[(size_t)(m0+row)*K + k0 + cg*8];
    } else {
      int row = tid>>3, cg = tid&7;
      *(ushort4*)&As[row*LP+cg*4] = *(const ushort4*)&Aa[(size_t)(m0+row)*K + k0 + cg*4];
    }
    if constexpr (BNt==64){
      int row = tid>>2, cg = tid&3;
      *(s16x8*)&Bs[row*LP+cg*8] = *(const s16x8*)&WT[(size_t)(n0+row)*K + k0 + cg*8];
    } else {
      int row = tid>>3, cg = tid&7;
      *(ushort4*)&Bs[row*LP+cg*4] = *(const ushort4*)&WT[(size_t)(n0+row)*K + k0 + cg*4];
    }
    __syncthreads();
    s16x8 af[FM], bv[FN];
    #pragma unroll
    for (int a=0;a<FM;++a) af[a] = *(const s16x8*)&As[(wm*WMm + a*16 + lc)*LP + lg*8];
    #pragma unroll
    for (int c=0;c<FN;++c) bv[c] = *(const s16x8*)&Bs[(wn*WNn + c*16 + lc)*LP + lg*8];
    #pragma unroll
    for (int a=0;a<FM;++a)
      #pragma unroll
      for (int c=0;c<FN;++c) acc[a][c] = mfma16(af[a], bv[c], acc[a][c]);
  }
  #pragma unroll
  for (int a=0;a<FM;++a){
    #pragma unroll
    for (int c=0;c<FN;++c){
      int n = n0 + wn*WNn + c*16 + lc;
      float bvv = (EPI!=0) ? bias[n] : 0.f;
      #pragma unroll
      for (int r=0;r<4;++r){
        int m = m0 + wm*WMm + a*16 + lg*4 + r;
        float vv = acc[a][c][r];
        if constexpr (EPI==0){
          ((unsigned short*)outv)[(size_t)m*NC + n] = f2bf(vv);
        } else if constexpr (EPI==1){
          ((float*)outv)[(size_t)m*NC + n] = vv + bvv + resid[(size_t)m*NC + n];
        } else {
          ((unsigned short*)outv)[(size_t)m*NC + n] = f2bf(gelu_f(vv + bvv));
        }
      }
    }
  }
}

extern "C" void kernel_launch(void* const* d_in, const int* in_sizes, int n_in,
                              void* d_out, int out_size, void* d_ws, size_t ws_size,
                              hipStream_t stream){
  const float* x_in  = (const float*)d_in[0];
  const float* coords= (const float*)d_in[1];
  const float* vel   = (const float*)d_in[2];
  const float* ln1_g = (const float*)d_in[3];
  const float* ln1_b = (const float*)d_in[4];
  const float* Wqkv  = (const float*)d_in[5];
  const float* relW1 = (const float*)d_in[6];
  const float* relb1 = (const float*)d_in[7];
  const float* relW2 = (const float*)d_in[8];
  const float* relb2 = (const float*)d_in[9];
  const float* Wout  = (const float*)d_in[10];
  const float* bout  = (const float*)d_in[11];
  const float* ln2_g = (const float*)d_in[12];
  const float* ln2_b = (const float*)d_in[13];
  const float* Wf1   = (const float*)d_in[14];
  const float* bf1   = (const float*)d_in[15];
  const float* Wf2   = (const float*)d_in[16];
  const float* bf2   = (const float*)d_in[17];

  float* x = (float*)d_out;
  unsigned short* us = (unsigned short*)d_ws;
  unsigned short* hbf   = us;                    // 524288
  unsigned short* qkvbf = hbf   + 524288;        // 1572864
  unsigned short* qbf   = qkvbf + 1572864;       // 524288
  unsigned short* kbf   = qbf   + 524288;        // 524288
  unsigned short* vbf   = kbf   + 524288;        // 524288
  unsigned short* attbf = vbf   + 524288;        // 524288
  unsigned short* midbf = attbf + 524288;        // 2097152
  unsigned short* relbf = midbf + 2097152;       // 16777216
  unsigned short* WqkvT = relbf + 16777216;      // 393216
  unsigned short* WoutT = WqkvT + 393216;        // 131072
  unsigned short* Wf1T  = WoutT + 131072;        // 524288
  unsigned short* Wf2T  = Wf1T  + 524288;        // 524288
  float* Arel = (float*)(Wf2T + 524288);         // 131072
  float* BTrel= Arel + 131072;                   // 131072
  float* sint = BTrel + 131072;                  // 16384
  float* cost = sint + 16384;                    // 16384

  hipMemcpyAsync(x, x_in, sizeof(float)*524288, hipMemcpyDeviceToDevice, stream);
  rope_table<<<64,256,0,stream>>>(sint,cost);
  // weight convert+transpose (both layers via z); Q-columns of Wqkv get SCALE
  wt_convert<<<dim3(24,8,2),256,0,stream>>>(Wqkv, WqkvT, 256, 768, 256, SCALEV);
  wt_convert<<<dim3(8,8,2),256,0,stream>>>(Wout, WoutT, 256, 256, 0, 1.0f);
  wt_convert<<<dim3(32,8,2),256,0,stream>>>(Wf1, Wf1T, 256, 1024, 0, 1.0f);
  wt_convert<<<dim3(8,32,2),256,0,stream>>>(Wf2, Wf2T, 1024, 256, 0, 1.0f);

  for (int l=0;l<2;++l){
    ln_kernel<<<2048,256,0,stream>>>(x, ln1_g+l*256, ln1_b+l*256, hbf);
    gemm_mfma<256,768,0,64,64><<<dim3(12,32),256,0,stream>>>(
        hbf, WqkvT + (size_t)l*196608, nullptr, nullptr, qkvbf);
    rope_apply_bf<<<2048,256,0,stream>>>(qkvbf, sint, cost, qbf, kbf, vbf);
    rel_pre<<<512,256,0,stream>>>(coords, vel, relW1+l*320, relb1+l*64, Arel, BTrel);
    rel_kernel2<<<4096,256,0,stream>>>(coords, vel, Arel, BTrel, relW1+l*320,
                                       relW2+l*512, relb2+l*8, (unsigned int*)relbf);
    attn_mfma<<<512,256,0,stream>>>(qbf, kbf, vbf, relbf, attbf);
    gemm_mfma<256,256,1,64,32><<<dim3(8,32),256,0,stream>>>(
        attbf, WoutT + (size_t)l*65536, bout+l*256, x, x);
    ln_kernel<<<2048,256,0,stream>>>(x, ln2_g+l*256, ln2_b+l*256, hbf);
    gemm_mfma<256,1024,2,64,64><<<dim3(16,32),256,0,stream>>>(
        hbf, Wf1T + (size_t)l*262144, bf1+l*1024, nullptr, midbf);
    gemm_mfma<1024,256,1,64,32><<<dim3(8,32),256,0,stream>>>(
        midbf, Wf2T + (size_t)l*262144, bf2+l*256, x, x);
  }
}